// Round 1
// 745.236 us; speedup vs baseline: 1.2865x; 1.2865x over previous
//
#include <hip/hip_runtime.h>
#include <cstdint>
#include <cstddef>

typedef short bf16x8 __attribute__((ext_vector_type(8)));
typedef float floatx4 __attribute__((ext_vector_type(4)));
typedef unsigned short ushort4v __attribute__((ext_vector_type(4)));

#define LN_EPS 1e-5f
#define ATTN_EPS 1e-8f
#define NCHUNK 16

__device__ __forceinline__ unsigned short f2bf(float f) {
    unsigned int u = __float_as_uint(f);
    u += 0x7fffu + ((u >> 16) & 1u);
    return (unsigned short)(u >> 16);
}

__device__ __forceinline__ void load_lds16(const void* gp, void* lp) {
    __builtin_amdgcn_global_load_lds(
        (__attribute__((address_space(1))) void*)gp,
        (__attribute__((address_space(3))) void*)lp,
        16, 0, 0);
}

// ---------------- LayerNorm over rows of 512, one wave per row ----------------
// QDOT: additionally write cbuf[row] = (LN'd scaled row) . wqbk
template<bool OUT_BF16, bool QDOT>
__global__ __launch_bounds__(256) void ln512_kernel(
        const float* __restrict__ x, const float* __restrict__ g, const float* __restrict__ b,
        void* __restrict__ out, int total_rows, int data_rows, float outscale,
        const float* __restrict__ wqbk, float* __restrict__ cbuf) {
    int row = blockIdx.x * 4 + (threadIdx.x >> 6);
    int lane = threadIdx.x & 63;
    if (row >= total_rows) return;
    int rr = row < data_rows ? row : data_rows - 1;
    const float4* xr = (const float4*)(x + (size_t)rr * 512);
    float4 a0 = xr[lane];
    float4 a1 = xr[lane + 64];
    float s  = a0.x + a0.y + a0.z + a0.w + a1.x + a1.y + a1.z + a1.w;
    float ss = a0.x*a0.x + a0.y*a0.y + a0.z*a0.z + a0.w*a0.w
             + a1.x*a1.x + a1.y*a1.y + a1.z*a1.z + a1.w*a1.w;
    #pragma unroll
    for (int off = 32; off > 0; off >>= 1) {
        s  += __shfl_xor(s, off, 64);
        ss += __shfl_xor(ss, off, 64);
    }
    float mu = s * (1.0f / 512.0f);
    float var = ss * (1.0f / 512.0f) - mu * mu;
    float rstd = rsqrtf(var + LN_EPS);
    float4 g0 = ((const float4*)g)[lane];
    float4 g1 = ((const float4*)g)[lane + 64];
    float4 b0 = ((const float4*)b)[lane];
    float4 b1 = ((const float4*)b)[lane + 64];
    float y[8];
    y[0] = ((a0.x - mu) * rstd * g0.x + b0.x) * outscale;
    y[1] = ((a0.y - mu) * rstd * g0.y + b0.y) * outscale;
    y[2] = ((a0.z - mu) * rstd * g0.z + b0.z) * outscale;
    y[3] = ((a0.w - mu) * rstd * g0.w + b0.w) * outscale;
    y[4] = ((a1.x - mu) * rstd * g1.x + b1.x) * outscale;
    y[5] = ((a1.y - mu) * rstd * g1.y + b1.y) * outscale;
    y[6] = ((a1.z - mu) * rstd * g1.z + b1.z) * outscale;
    y[7] = ((a1.w - mu) * rstd * g1.w + b1.w) * outscale;
    if (QDOT) {
        float4 w0 = ((const float4*)wqbk)[lane];
        float4 w1 = ((const float4*)wqbk)[lane + 64];
        float cd = y[0]*w0.x + y[1]*w0.y + y[2]*w0.z + y[3]*w0.w
                 + y[4]*w1.x + y[5]*w1.y + y[6]*w1.z + y[7]*w1.w;
        #pragma unroll
        for (int off = 32; off > 0; off >>= 1) cd += __shfl_xor(cd, off, 64);
        if (lane == 0) cbuf[row] = cd;
    }
    if (OUT_BF16) {
        unsigned short* orow = (unsigned short*)out + (size_t)row * 512;
        ushort4v o0, o1;
        o0.x = f2bf(y[0]); o0.y = f2bf(y[1]); o0.z = f2bf(y[2]); o0.w = f2bf(y[3]);
        o1.x = f2bf(y[4]); o1.y = f2bf(y[5]); o1.z = f2bf(y[6]); o1.w = f2bf(y[7]);
        *(ushort4v*)(orow + lane * 4) = o0;
        *(ushort4v*)(orow + 256 + lane * 4) = o1;
    } else {
        float* orow = (float*)out + (size_t)row * 512;
        *(float4*)(orow + lane * 4) = make_float4(y[0], y[1], y[2], y[3]);
        *(float4*)(orow + 256 + lane * 4) = make_float4(y[4], y[5], y[6], y[7]);
    }
}

// ---------------- fused one-time prep ----------------
__device__ __forceinline__ void tr32(const float* __restrict__ in, unsigned short* __restrict__ out,
                                     int R, int C, int bx, int by, float (*tile)[33]) {
    int tx = threadIdx.x & 31, ty = threadIdx.x >> 5;
    #pragma unroll
    for (int i = 0; i < 32; i += 8)
        tile[ty + i][tx] = in[(size_t)(by + ty + i) * C + bx + tx];
    __syncthreads();
    #pragma unroll
    for (int i = 0; i < 32; i += 8)
        out[(size_t)(bx + ty + i) * R + by + tx] = f2bf(tile[tx][ty + i]);
}

// row-dot: out[row] = in[row][0..512) . vec   (wave per row)
__device__ __forceinline__ void rowdot512(const float* __restrict__ in, const float* __restrict__ vec,
                                          float* __restrict__ out, int row) {
    int lane = threadIdx.x & 63;
    const float4* r0 = (const float4*)(in + (size_t)row * 512);
    float4 a0 = r0[lane], a1 = r0[lane + 64];
    float4 v0 = ((const float4*)vec)[lane], v1 = ((const float4*)vec)[lane + 64];
    float d = a0.x*v0.x + a0.y*v0.y + a0.z*v0.z + a0.w*v0.w
            + a1.x*v1.x + a1.y*v1.y + a1.z*v1.z + a1.w*v1.w;
    #pragma unroll
    for (int off = 32; off > 0; off >>= 1) d += __shfl_xor(d, off, 64);
    if (lane == 0) out[row] = d;
}

__global__ __launch_bounds__(256) void prep_all(
        const float* __restrict__ Wk, const float* __restrict__ Wq,
        const float* __restrict__ Wv, const float* __restrict__ W_ih,
        const float* __restrict__ W_hh, const float* __restrict__ W1,
        const float* __restrict__ W2, const float* __restrict__ slots_in,
        const float* __restrict__ bk, const float* __restrict__ bv,
        unsigned short* __restrict__ Wk_b, unsigned short* __restrict__ Wq_b,
        unsigned short* __restrict__ Wv_b, unsigned short* __restrict__ Wih_b,
        unsigned short* __restrict__ Whh_b, unsigned short* __restrict__ W1T,
        unsigned short* __restrict__ W2T, unsigned short* __restrict__ slbf,
        float* __restrict__ wqbk, float* __restrict__ bvW) {
    __shared__ float tile[32][33];
    const int b = blockIdx.x;
    const int t = threadIdx.x;
    if (b < 1024) {                       // Wk convert [512][512]
        int idx = b * 256 + t; Wk_b[idx] = f2bf(Wk[idx]);
    } else if (b < 2048) {                // Wq convert
        int idx = (b - 1024) * 256 + t; Wq_b[idx] = f2bf(Wq[idx]);
    } else if (b < 3072) {                // Wv convert
        int idx = (b - 2048) * 256 + t; Wv_b[idx] = f2bf(Wv[idx]);
    } else if (b < 6144) {                // Wih convert [1536][512]
        int idx = (b - 3072) * 256 + t; Wih_b[idx] = f2bf(W_ih[idx]);
    } else if (b < 9216) {                // Whh convert
        int idx = (b - 6144) * 256 + t; Whh_b[idx] = f2bf(W_hh[idx]);
    } else if (b < 10240) {               // W1 [512][2048] -> W1T [2048][512]
        int i = b - 9216;
        tr32(W1, W1T, 512, 2048, (i & 63) * 32, (i >> 6) * 32, tile);
    } else if (b < 11264) {               // W2 [2048][512] -> W2T [512][2048]
        int i = b - 10240;
        tr32(W2, W2T, 2048, 512, (i & 15) * 32, (i >> 4) * 32, tile);
    } else if (b < 12032) {               // slbf: bf16 slots, 384-row padded
        int idx = (b - 11264) * 256 + t;
        int row = idx >> 9, d = idx & 511;
        int rr = row < 352 ? row : 351;
        slbf[idx] = f2bf(slots_in[(size_t)rr * 512 + d]);
    } else if (b < 12160) {               // wqbk[din] = Wq[din] . bk  (512 rows)
        int row = (b - 12032) * 4 + (t >> 6);
        rowdot512(Wq, bk, wqbk, row);
    } else {                              // bvW[n3] = W_ih[n3] . bv  (1536 rows)
        int row = (b - 12160) * 4 + (t >> 6);
        rowdot512(W_ih, bv, bvW, row);
    }
}

// ---------------- bf16 MFMA GEMM core: 64x64 tile, BK=64, swizzled LDS ----------------
// BMODE: 0 none, 1 +bias[n], 2 +bias[n]+coef[m]*bvW[n].  OUT_MODE: 0 fp32, 1 bf16, 2 both.
template<int BMODE, bool RELU, int OUT_MODE>
__device__ __forceinline__ void hgemm_core(
        const unsigned short* __restrict__ A, const unsigned short* __restrict__ Bt,
        const float* __restrict__ bias, const float* __restrict__ bvW,
        const float* __restrict__ coef, float* __restrict__ Cf,
        unsigned short* __restrict__ Cb, int m0, int n0, int N, int K,
        unsigned short* As, unsigned short* Bs) {
    const int t = threadIdx.x;
    const int lane = t & 63;
    const int w = t >> 6;
    const int wm = w >> 1, wn = w & 1;
    const int quad = lane >> 4;
    const int l15 = lane & 15;
    floatx4 acc[2][2];
    #pragma unroll
    for (int i = 0; i < 2; ++i)
        #pragma unroll
        for (int j = 0; j < 2; ++j)
            #pragma unroll
            for (int r = 0; r < 4; ++r) acc[i][j][r] = 0.0f;

    for (int k0 = 0; k0 < K; k0 += 64) {
        #pragma unroll
        for (int p = 0; p < 2; ++p) {
            const int s = p * 256 + t;
            const int row = s >> 3;
            const int c = (s & 7) ^ (row & 7);
            const int ldsoff = (s - lane) * 16;
            load_lds16(A  + (size_t)(m0 + row) * K + k0 + c * 8, (char*)As + ldsoff);
            load_lds16(Bt + (size_t)(n0 + row) * K + k0 + c * 8, (char*)Bs + ldsoff);
        }
        __builtin_amdgcn_s_waitcnt(0);
        __syncthreads();
        #pragma unroll
        for (int h = 0; h < 2; ++h) {
            bf16x8 af[2], bfr[2];
            #pragma unroll
            for (int i = 0; i < 2; ++i) {
                const int row = wm * 32 + i * 16 + l15;
                const int cp = ((h << 2) | quad) ^ (l15 & 7);
                af[i] = *(const bf16x8*)(As + row * 64 + cp * 8);
            }
            #pragma unroll
            for (int j = 0; j < 2; ++j) {
                const int row = wn * 32 + j * 16 + l15;
                const int cp = ((h << 2) | quad) ^ (l15 & 7);
                bfr[j] = *(const bf16x8*)(Bs + row * 64 + cp * 8);
            }
            #pragma unroll
            for (int i = 0; i < 2; ++i)
                #pragma unroll
                for (int j = 0; j < 2; ++j)
                    acc[i][j] = __builtin_amdgcn_mfma_f32_16x16x32_bf16(af[i], bfr[j], acc[i][j], 0, 0, 0);
        }
        __syncthreads();
    }
    #pragma unroll
    for (int j = 0; j < 2; ++j) {
        const int n = n0 + wn * 32 + j * 16 + l15;
        const float bb = (BMODE >= 1) ? bias[n] : 0.0f;
        const float bw = (BMODE == 2) ? bvW[n] : 0.0f;
        #pragma unroll
        for (int i = 0; i < 2; ++i) {
            #pragma unroll
            for (int r = 0; r < 4; ++r) {
                const int m = m0 + wm * 32 + i * 16 + quad * 4 + r;
                float v = acc[i][j][r] + bb;
                if (BMODE == 2) v += coef[m] * bw;
                if (RELU) v = fmaxf(v, 0.0f);
                if (OUT_MODE == 0 || OUT_MODE == 2) Cf[(size_t)m * N + n] = v;
                if (OUT_MODE == 1 || OUT_MODE == 2) Cb[(size_t)m * N + n] = f2bf(v);
            }
        }
    }
}

template<int BMODE, bool RELU, int OUT_MODE>
__global__ __launch_bounds__(256) void hgemm(
        const unsigned short* __restrict__ A, const unsigned short* __restrict__ Bt,
        const float* __restrict__ bias, float* __restrict__ Cf,
        unsigned short* __restrict__ Cb, int N, int K) {
    __shared__ unsigned short As[64 * 64];
    __shared__ unsigned short Bs[64 * 64];
    hgemm_core<BMODE, RELU, OUT_MODE>(A, Bt, bias, nullptr, nullptr, Cf, Cb,
                                      blockIdx.y * 64, blockIdx.x * 64, N, K, As, Bs);
}

// one-time weight-composition GEMMs: z=0 WqkT = Wk@Wq^T ; z=1 Wc = Wih@Wv^T
__global__ __launch_bounds__(256) void prep_gemms(
        const unsigned short* __restrict__ Wk_b, const unsigned short* __restrict__ Wq_b,
        const unsigned short* __restrict__ Wih_b, const unsigned short* __restrict__ Wv_b,
        unsigned short* __restrict__ WqkT, unsigned short* __restrict__ Wc) {
    __shared__ unsigned short As[64 * 64];
    __shared__ unsigned short Bs[64 * 64];
    if (blockIdx.z == 0) {
        if (blockIdx.y >= 8) return;
        hgemm_core<0, false, 1>(Wk_b, Wq_b, nullptr, nullptr, nullptr, nullptr, WqkT,
                                blockIdx.y * 64, blockIdx.x * 64, 512, 512, As, Bs);
    } else {
        hgemm_core<0, false, 1>(Wih_b, Wv_b, nullptr, nullptr, nullptr, nullptr, Wc,
                                blockIdx.y * 64, blockIdx.x * 64, 512, 512, As, Bs);
    }
}

// gi and gh in one launch (blockIdx.z selects)
__global__ __launch_bounds__(256) void gru_gemm(
        const unsigned short* __restrict__ Pn, const unsigned short* __restrict__ slbf,
        const unsigned short* __restrict__ Wc, const unsigned short* __restrict__ Whh,
        const float* __restrict__ bih, const float* __restrict__ bhh,
        const float* __restrict__ bvW, const float* __restrict__ coef,
        float* __restrict__ gi, float* __restrict__ gh) {
    __shared__ unsigned short As[64 * 64];
    __shared__ unsigned short Bs[64 * 64];
    if (blockIdx.z == 0)
        hgemm_core<2, false, 0>(Pn, Wc, bih, bvW, coef, gi, nullptr,
                                blockIdx.y * 64, blockIdx.x * 64, 1536, 512, As, Bs);
    else
        hgemm_core<1, false, 0>(slbf, Whh, bhh, nullptr, nullptr, gh, nullptr,
                                blockIdx.y * 64, blockIdx.x * 64, 1536, 512, As, Bs);
}

// ---------------- hybrid MFMA inverted attention over xln ----------------
// QK^T via mfma_f32_16x16x32_bf16 (A = qp_b bf16 fragments in regs, B = xln read
// direct from global in B-frag layout); softmax over s in C-layout (2 shfl_xor);
// attn broadcast through per-wave LDS tile; AV stays VALU with U[11][8] in regs
// (AV re-reads the 16 KB tile just streamed by QK -> L1-resident).
__global__ __launch_bounds__(256, 2) void attn_kernel(
        const unsigned short* __restrict__ qp_b, const unsigned short* __restrict__ xln,
        const float* __restrict__ cbuf,
        float* __restrict__ Up, float* __restrict__ rsp) {
    const int b = blockIdx.y;
    const int chunk = blockIdx.x;
    const int w = threadIdx.x >> 6, lane = threadIdx.x & 63;
    const int l15 = lane & 15, quad = lane >> 4;
    const int d0 = lane * 8;
    const int NPC = 4096 / NCHUNK;   // 256

    __shared__ float attnlds[4][16][20];   // [wave][n-local][s(padded)]
    __shared__ float Us[11 * 512];
    __shared__ float rss[11];

    // A-fragments: lane holds qp[s=l15][k = ks*32 + quad*8 + j]  (rows clamped for s>=11)
    const unsigned short* qrow = qp_b + (size_t)(b * 11 + (l15 < 11 ? l15 : 10)) * 512 + quad * 8;
    bf16x8 aq[16];
    #pragma unroll
    for (int ks = 0; ks < 16; ++ks) aq[ks] = *(const bf16x8*)(qrow + ks * 32);

    float cb[4];
    #pragma unroll
    for (int r = 0; r < 4; ++r) {
        int s = quad * 4 + r;
        cb[r] = (s < 11) ? cbuf[b * 11 + s] : 0.0f;
    }

    float U[11][8];
    float rs[11];
    #pragma unroll
    for (int s = 0; s < 11; ++s) {
        rs[s] = 0.f;
        #pragma unroll
        for (int j = 0; j < 8; ++j) U[s][j] = 0.f;
    }

    const unsigned short* xbase = xln + ((size_t)b * 4096 + (size_t)chunk * NPC) * 512;

    for (int t = 0; t < NPC / 64; ++t) {
        const int n0 = t * 64 + w * 16;           // this wave's 16-n tile
        // ---- QK: 16 MFMA k-steps, B-frags direct from global ----
        const unsigned short* krow = xbase + (size_t)(n0 + l15) * 512 + quad * 8;
        floatx4 c;
        c[0] = c[1] = c[2] = c[3] = 0.0f;
        #pragma unroll
        for (int ks = 0; ks < 16; ++ks) {
            bf16x8 bf = *(const bf16x8*)(krow + ks * 32);
            c = __builtin_amdgcn_mfma_f32_16x16x32_bf16(aq[ks], bf, c, 0, 0, 0);
        }
        // logits: c[r] = logit[s = quad*4+r][n = n0+l15]
        float l0 = c[0] + cb[0], l1 = c[1] + cb[1], l2 = c[2] + cb[2], l3 = c[3] + cb[3];
        if (quad == 2) l3 = -1e30f;
        if (quad == 3) { l0 = -1e30f; l1 = -1e30f; l2 = -1e30f; l3 = -1e30f; }
        // softmax over s (column reduction = 2 shuffles across quads)
        float mx = fmaxf(fmaxf(l0, l1), fmaxf(l2, l3));
        mx = fmaxf(mx, __shfl_xor(mx, 16, 64));
        mx = fmaxf(mx, __shfl_xor(mx, 32, 64));
        float e0 = __expf(l0 - mx), e1 = __expf(l1 - mx),
              e2 = __expf(l2 - mx), e3 = __expf(l3 - mx);
        float se = e0 + e1 + e2 + e3;
        se += __shfl_xor(se, 16, 64);
        se += __shfl_xor(se, 32, 64);
        float inv = 1.0f / se;
        float4 av = make_float4(e0 * inv, e1 * inv, e2 * inv, e3 * inv);
        *(float4*)&attnlds[w][l15][quad * 4] = av;   // wave-local, in-order LDS pipe
        __builtin_amdgcn_wave_barrier();
        // ---- AV: lane owns d0..d0+7, iterate this wave's 16 n (L1-hot rows) ----
        for (int nl = 0; nl < 16; ++nl) {
            uint4 kr = *(const uint4*)(xbase + (size_t)(n0 + nl) * 512 + d0);
            float kf[8];
            kf[0] = __uint_as_float(kr.x << 16); kf[1] = __uint_as_float(kr.x & 0xffff0000u);
            kf[2] = __uint_as_float(kr.y << 16); kf[3] = __uint_as_float(kr.y & 0xffff0000u);
            kf[4] = __uint_as_float(kr.z << 16); kf[5] = __uint_as_float(kr.z & 0xffff0000u);
            kf[6] = __uint_as_float(kr.w << 16); kf[7] = __uint_as_float(kr.w & 0xffff0000u);
            float4 a0 = *(const float4*)&attnlds[w][nl][0];
            float4 a1 = *(const float4*)&attnlds[w][nl][4];
            float4 a2 = *(const float4*)&attnlds[w][nl][8];
            float as[11] = {a0.x, a0.y, a0.z, a0.w, a1.x, a1.y, a1.z, a1.w,
                            a2.x, a2.y, a2.z};
            #pragma unroll
            for (int s = 0; s < 11; ++s) {
                rs[s] += as[s];
                #pragma unroll
                for (int j = 0; j < 8; ++j) U[s][j] = fmaf(as[s], kf[j], U[s][j]);
            }
        }
    }

    // ---- cross-wave reduce of U and rs (phase-summed) ----
    for (int ph = 0; ph < 4; ++ph) {
        if (w == ph) {
            #pragma unroll
            for (int s = 0; s < 11; ++s) {
                #pragma unroll
                for (int j = 0; j < 8; ++j) {
                    if (ph == 0) Us[s * 512 + d0 + j] = U[s][j];
                    else         Us[s * 512 + d0 + j] += U[s][j];
                }
            }
            if (lane == 0) {
                #pragma unroll
                for (int s = 0; s < 11; ++s) {
                    if (ph == 0) rss[s] = rs[s]; else rss[s] += rs[s];
                }
            }
        }
        __syncthreads();
    }
    float* up = Up + ((size_t)b * NCHUNK + chunk) * 11 * 512;
    for (int idx = threadIdx.x; idx < 11 * 512; idx += 256) up[idx] = Us[idx];
    if (threadIdx.x < 11) rsp[((size_t)b * NCHUNK + chunk) * 11 + threadIdx.x] = rss[threadIdx.x];
}

// ------------- reduce partials -> Pn(bf16) = U/(rs+eps), coef = rs/(rs+eps) -------------
__global__ __launch_bounds__(256) void attn_reduce(
        const float* __restrict__ Up, const float* __restrict__ rsp,
        unsigned short* __restrict__ Pn, float* __restrict__ coef) {
    const int bs = blockIdx.x;  // grid 384 (pad rows -> zeros)
    if (bs >= 352) {
        for (int d = threadIdx.x; d < 512; d += 256) Pn[(size_t)bs * 512 + d] = 0;
        if (threadIdx.x == 0) coef[bs] = 0.0f;
        return;
    }
    const int b = bs / 11, s = bs - b * 11;
    float rsum = 0.0f;
    #pragma unroll
    for (int c = 0; c < NCHUNK; ++c) rsum += rsp[((size_t)b * NCHUNK + c) * 11 + s];
    const float inv = 1.0f / (rsum + ATTN_EPS);
    if (threadIdx.x == 0) coef[bs] = rsum * inv;
    for (int d = threadIdx.x; d < 512; d += 256) {
        float acc = 0.f;
        #pragma unroll
        for (int c = 0; c < NCHUNK; ++c) acc += Up[(((size_t)b * NCHUNK + c) * 11 + s) * 512 + d];
        Pn[(size_t)bs * 512 + d] = f2bf(acc * inv);
    }
}

// ---------------- fused GRU + MLP-LayerNorm: gi,gh,slots -> mln(bf16) ----------------
__global__ __launch_bounds__(256) void gru_ln(
        const float* __restrict__ gi, const float* __restrict__ gh,
        const float* __restrict__ slots, const float* __restrict__ g,
        const float* __restrict__ b, unsigned short* __restrict__ mln) {
    int row = blockIdx.x * 4 + (threadIdx.x >> 6);
    int lane = threadIdx.x & 63;
    unsigned short* orow = mln + (size_t)row * 512;
    if (row >= 352) {
        ushort4v z; z.x = z.y = z.z = z.w = 0;
        *(ushort4v*)(orow + lane * 4) = z;
        *(ushort4v*)(orow + 256 + lane * 4) = z;
        return;
    }
    const float4* gir = (const float4*)(gi + (size_t)row * 1536);
    const float4* ghr = (const float4*)(gh + (size_t)row * 1536);
    const float4* sr  = (const float4*)(slots + (size_t)row * 512);
    float v[8];
    #pragma unroll
    for (int half = 0; half < 2; ++half) {
        int o = half * 64 + lane;
        float4 ir = gir[o], iz = gir[128 + o], in_ = gir[256 + o];
        float4 hr = ghr[o], hz = ghr[128 + o], hn = ghr[256 + o];
        float4 sv = sr[o];
        float rr[4], zz[4], nn[4];
        rr[0] = 1.f / (1.f + __expf(-(ir.x + hr.x)));
        rr[1] = 1.f / (1.f + __expf(-(ir.y + hr.y)));
        rr[2] = 1.f / (1.f + __expf(-(ir.z + hr.z)));
        rr[3] = 1.f / (1.f + __expf(-(ir.w + hr.w)));
        zz[0] = 1.f / (1.f + __expf(-(iz.x + hz.x)));
        zz[1] = 1.f / (1.f + __expf(-(iz.y + hz.y)));
        zz[2] = 1.f / (1.f + __expf(-(iz.z + hz.z)));
        zz[3] = 1.f / (1.f + __expf(-(iz.w + hz.w)));
        nn[0] = tanhf(in_.x + rr[0] * hn.x);
        nn[1] = tanhf(in_.y + rr[1] * hn.y);
        nn[2] = tanhf(in_.z + rr[2] * hn.z);
        nn[3] = tanhf(in_.w + rr[3] * hn.w);
        v[half * 4 + 0] = (1.f - zz[0]) * nn[0] + zz[0] * sv.x;
        v[half * 4 + 1] = (1.f - zz[1]) * nn[1] + zz[1] * sv.y;
        v[half * 4 + 2] = (1.f - zz[2]) * nn[2] + zz[2] * sv.z;
        v[half * 4 + 3] = (1.f - zz[3]) * nn[3] + zz[3] * sv.w;
    }
    float s = 0.f, ss = 0.f;
    #pragma unroll
    for (int j = 0; j < 8; ++j) { s += v[j]; ss += v[j] * v[j]; }
    #pragma unroll
    for (int off = 32; off > 0; off >>= 1) {
        s  += __shfl_xor(s, off, 64);
        ss += __shfl_xor(ss, off, 64);
    }
    float mu = s * (1.0f / 512.0f);
    float var = ss * (1.0f / 512.0f) - mu * mu;
    float rstd = rsqrtf(var + LN_EPS);
    float4 g0 = ((const float4*)g)[lane], g1 = ((const float4*)g)[lane + 64];
    float4 b0 = ((const float4*)b)[lane], b1 = ((const float4*)b)[lane + 64];
    ushort4v o0, o1;
    o0.x = f2bf((v[0] - mu) * rstd * g0.x + b0.x);
    o0.y = f2bf((v[1] - mu) * rstd * g0.y + b0.y);
    o0.z = f2bf((v[2] - mu) * rstd * g0.z + b0.z);
    o0.w = f2bf((v[3] - mu) * rstd * g0.w + b0.w);
    o1.x = f2bf((v[4] - mu) * rstd * g1.x + b1.x);
    o1.y = f2bf((v[5] - mu) * rstd * g1.y + b1.y);
    o1.z = f2bf((v[6] - mu) * rstd * g1.z + b1.z);
    o1.w = f2bf((v[7] - mu) * rstd * g1.w + b1.w);
    *(ushort4v*)(orow + lane * 4) = o0;
    *(ushort4v*)(orow + 256 + lane * 4) = o1;
}

extern "C" void kernel_launch(void* const* d_in, const int* in_sizes, int n_in,
                              void* d_out, int out_size, void* d_ws, size_t ws_size,
                              hipStream_t stream) {
    const float* slots_in = (const float*)d_in[0];
    const float* inputs   = (const float*)d_in[1];
    const float* ln_in_g  = (const float*)d_in[2];
    const float* ln_in_b  = (const float*)d_in[3];
    const float* Wk  = (const float*)d_in[4];
    const float* bk  = (const float*)d_in[5];
    const float* Wv  = (const float*)d_in[6];
    const float* bv  = (const float*)d_in[7];
    const float* ln_q_g = (const float*)d_in[8];
    const float* ln_q_b = (const float*)d_in[9];
    const float* Wq  = (const float*)d_in[10];
    const float* W_ih = (const float*)d_in[11];
    const float* b_ih = (const float*)d_in[12];
    const float* W_hh = (const float*)d_in[13];
    const float* b_hh = (const float*)d_in[14];
    const float* ln_m_g = (const float*)d_in[15];
    const float* ln_m_b = (const float*)d_in[16];
    const float* W1 = (const float*)d_in[17];
    const float* b1 = (const float*)d_in[18];
    const float* W2 = (const float*)d_in[19];
    const float* b2 = (const float*)d_in[20];

    char* p = (char*)d_ws;
    auto alloc = [&](size_t bytes) { char* r = p; p += (bytes + 255) & ~(size_t)255; return r; };
    unsigned short* xln   = (unsigned short*)alloc(131072ull * 512 * 2);
    unsigned short* Wk_b  = (unsigned short*)alloc(512ull * 512 * 2);
    unsigned short* Wq_b  = (unsigned short*)alloc(512ull * 512 * 2);
    unsigned short* Wv_b  = (unsigned short*)alloc(512ull * 512 * 2);
    unsigned short* Wih_b = (unsigned short*)alloc(1536ull * 512 * 2);
    unsigned short* Whh_b = (unsigned short*)alloc(1536ull * 512 * 2);
    unsigned short* WqkT  = (unsigned short*)alloc(512ull * 512 * 2);
    unsigned short* Wc    = (unsigned short*)alloc(1536ull * 512 * 2);
    unsigned short* W1T   = (unsigned short*)alloc(2048ull * 512 * 2);
    unsigned short* W2T   = (unsigned short*)alloc(512ull * 2048 * 2);
    unsigned short* slq   = (unsigned short*)alloc(384ull * 512 * 2);
    unsigned short* mln   = (unsigned short*)alloc(384ull * 512 * 2);
    unsigned short* Pn    = (unsigned short*)alloc(384ull * 512 * 2);
    unsigned short* slbf  = (unsigned short*)alloc(384ull * 512 * 2);
    unsigned short* h1    = (unsigned short*)alloc(384ull * 2048 * 2);
    unsigned short* qp_b  = (unsigned short*)alloc(384ull * 512 * 2);
    float* slots = (float*)alloc(384ull * 512 * 4);
    float* gi    = (float*)alloc(384ull * 1536 * 4);
    float* gh    = (float*)alloc(384ull * 1536 * 4);
    float* Up    = (float*)alloc((size_t)32 * NCHUNK * 11 * 512 * 4);
    float* rsp   = (float*)alloc((size_t)32 * NCHUNK * 11 * 4);
    float* wqbk  = (float*)alloc(512 * 4);
    float* bvW   = (float*)alloc(1536 * 4);
    float* cbuf  = (float*)alloc(384 * 4);
    float* coef  = (float*)alloc(384 * 4);

    // ---- one-time prep ----
    ln512_kernel<true, false><<<dim3(32768), 256, 0, stream>>>(
        inputs, ln_in_g, ln_in_b, xln, 131072, 131072, 1.0f, nullptr, nullptr);
    prep_all<<<dim3(12544), 256, 0, stream>>>(
        Wk, Wq, Wv, W_ih, W_hh, W1, W2, slots_in, bk, bv,
        Wk_b, Wq_b, Wv_b, Wih_b, Whh_b, W1T, W2T, slbf, wqbk, bvW);
    prep_gemms<<<dim3(8, 24, 2), 256, 0, stream>>>(Wk_b, Wq_b, Wih_b, Wv_b, WqkT, Wc);
    hipMemcpyAsync(slots, slots_in, 352ull * 512 * 4, hipMemcpyDeviceToDevice, stream);

    const float qscale = 0.044194173824159216f;  // 1/sqrt(512)
    for (int it = 0; it < 3; ++it) {
        ln512_kernel<true, true><<<dim3(96), 256, 0, stream>>>(
            slots, ln_q_g, ln_q_b, slq, 384, 352, qscale, wqbk, cbuf);
        hgemm<0, false, 1><<<dim3(8, 6), 256, 0, stream>>>(slq, WqkT, nullptr, nullptr, qp_b, 512, 512);
        attn_kernel<<<dim3(NCHUNK, 32), 256, 0, stream>>>(qp_b, xln, cbuf, Up, rsp);
        attn_reduce<<<dim3(384), 256, 0, stream>>>(Up, rsp, Pn, coef);
        gru_gemm<<<dim3(24, 6, 2), 256, 0, stream>>>(Pn, slbf, Wc, Whh_b, b_ih, b_hh, bvW, coef, gi, gh);
        gru_ln<<<dim3(96), 256, 0, stream>>>(gi, gh, slots, ln_m_g, ln_m_b, mln);
        hgemm<1, true, 1><<<dim3(32, 6), 256, 0, stream>>>(mln, W1T, b1, nullptr, h1, 2048, 512);
        hgemm<1, false, 2><<<dim3(8, 6), 256, 0, stream>>>(h1, W2T, b2, slots, slbf, 512, 2048);
    }
    hipMemcpyAsync(d_out, slots, (size_t)out_size * 4, hipMemcpyDeviceToDevice, stream);
}